// Round 2
// baseline (12241.280 us; speedup 1.0000x reference)
//
#include <hip/hip_runtime.h>

#define B_    1024
#define T_    256
#define LOCN  40001
#define E_    100
#define H_    100
#define NC    600   // [0,400): gates (i|f|g|o) preact, [400,500): t preact, [500,600): s preact

// ---------------------------------------------------------------------------
// Kernel 1: P_loc[LOC][600] = emb_loc @ [W_ih | W_xt | W_xs] + [b | b_t | b_s]
// (round-0 proven version, PROWS=16)
// ---------------------------------------------------------------------------
constexpr int PROWS = 16;
constexpr int PPAD  = 20;   // pad 16->20 dwords: keeps 16B alignment, breaks pow2 bank stride

__global__ __launch_bounds__(320) void proj_loc_kernel(
    const float* __restrict__ emb_loc,
    const float* __restrict__ W_ih,   // [100][400]
    const float* __restrict__ W_xt,   // [100][100]
    const float* __restrict__ W_xs,   // [100][100]
    const float* __restrict__ b,      // [400]
    const float* __restrict__ b_t,    // [100]
    const float* __restrict__ b_s,    // [100]
    float* __restrict__ P)            // [LOC][600]
{
    __shared__ __attribute__((aligned(16))) float aT[E_][PPAD];  // transposed tile
    const int tid  = threadIdx.x;
    const int row0 = blockIdx.x * PROWS;

    for (int i = tid; i < PROWS * E_; i += 320) {
        int r = i / E_, k = i - r * E_;
        int rr = row0 + r;
        float v = 0.f;
        if (rr < LOCN) v = emb_loc[rr * E_ + k];
        aT[k][r] = v;
    }
    __syncthreads();
    if (tid >= 300) return;

    for (int cc = 0; cc < 2; ++cc) {
        const int c = tid + cc * 300;
        const float* wp; int stride; float bias;
        if (c < 400)      { wp = W_ih + c;         stride = 400; bias = b[c]; }
        else if (c < 500) { wp = W_xt + (c - 400); stride = 100; bias = b_t[c - 400]; }
        else              { wp = W_xs + (c - 500); stride = 100; bias = b_s[c - 500]; }

        float acc[PROWS];
        #pragma unroll
        for (int r = 0; r < PROWS; ++r) acc[r] = bias;

        for (int k = 0; k < E_; ++k) {
            float wv = wp[(size_t)k * stride];
            #pragma unroll
            for (int r = 0; r < PROWS; ++r) acc[r] += aT[k][r] * wv;
        }
        #pragma unroll
        for (int r = 0; r < PROWS; ++r) {
            int rr = row0 + r;
            if (rr < LOCN) P[(size_t)rr * NC + c] = acc[r];
        }
    }
}

// ---------------------------------------------------------------------------
// Kernel 2: P_t[92][100] = emb_t @ W_tt ; P_s[92][100] = emb_s @ W_ss
// ---------------------------------------------------------------------------
__global__ void proj_ts_kernel(
    const float* __restrict__ emb_t, const float* __restrict__ emb_s,
    const float* __restrict__ W_tt,  const float* __restrict__ W_ss,
    float* __restrict__ P_t, float* __restrict__ P_s)
{
    int idx = blockIdx.x * 256 + threadIdx.x;
    if (idx >= 2 * 92 * H_) return;
    int which = idx / (92 * H_);
    int rem   = idx - which * (92 * H_);
    int r = rem / H_, c = rem - r * H_;
    const float* e = which ? emb_s : emb_t;
    const float* W = which ? W_ss : W_tt;
    float acc = 0.f;
    #pragma unroll
    for (int k = 0; k < 12; ++k) acc += e[r * 12 + k] * W[k * H_ + c];
    (which ? P_s : P_t)[rem] = acc;
}

// ---------------------------------------------------------------------------
// Kernel 3: recurrence. 256 blocks x 1024 threads, RB=4 rows/block, 1 blk/CU.
//   tid [0,800)    : gate threads. thread = (q=tid>>3, gi=(tid>>1)&3, half=tid&1)
//                    holds w[52] = W_hh[half*52 .. +52)[gi*100+q] in VGPRs
//                    (k 100..103 zero-padded). Pair-reduce via shfl_xor(1);
//                    i/f/g/o gathered via shfl_xor(2/4) within 8-lane group.
//                    No gates_lds, ONE raw barrier per step (lgkmcnt only).
//   tid [800,1000) : t/s gate channel ch=tid-800, pipelined one step ahead
//                    into double-buffered tg/sg_lds (proven round-1 scheme).
//   tid [1000,1024): idle (wave 15 still has active gate lanes -> barrier ok).
// ---------------------------------------------------------------------------
constexpr int RB = 4;
constexpr int NT = 1024;
constexpr int HP = 104;   // padded h length = 2*52

__global__ __launch_bounds__(NT) void lstm_rec_kernel(
    const int* __restrict__ traj,
    const int* __restrict__ traj_len_p,
    const int* __restrict__ tu,      const int* __restrict__ tl,
    const int* __restrict__ tu_slot, const int* __restrict__ tl_slot,
    const int* __restrict__ su,      const int* __restrict__ sl,
    const int* __restrict__ su_slot, const int* __restrict__ sl_slot,
    const float* __restrict__ P,     // [LOC][600]
    const float* __restrict__ P_t,   // [92][100]
    const float* __restrict__ P_s,   // [92][100]
    const float* __restrict__ W_hh,  // [100][400]
    float* __restrict__ out)         // [B][100]
{
    __shared__ __attribute__((aligned(16))) float h_lds[2][RB][HP];
    __shared__ float tg_lds[2][RB][H_];
    __shared__ float sg_lds[2][RB][H_];

    const int tid = threadIdx.x;
    const int b0  = blockIdx.x * RB;
    int steps = traj_len_p[0] + 1;
    if (steps > T_) steps = T_;
    steps = __builtin_amdgcn_readfirstlane(steps);
    const int t1c = (steps > 1) ? 1 : 0;
    const int t2c = (steps > 2) ? 2 : steps - 1;

    // zero both h buffers (incl. pad [100,104) which must stay 0 forever)
    for (int i = tid; i < 2 * RB * HP; i += NT) ((float*)h_lds)[i] = 0.f;

    const bool isGate = (tid < 800);
    const bool isTS   = (tid >= 800) && (tid < 1000);

    // ---- gate-role constants ----
    const int half  = tid & 1;
    const int gi    = (tid >> 1) & 3;     // 0=i 1=f 2=g 3=o
    const int q     = tid >> 3;           // h-index (tid<800 -> q<100)
    const int n     = gi * 100 + q;       // W_hh / P column
    const int kbase = half * 52;

    // ---- ts-role constants ----
    const int  ch   = tid - 800;          // 0..199 when isTS
    const bool is_t = ch < 100;
    const int  hx   = is_t ? ch : ch - 100;
    const int  gcol = 400 + ch;
    const int* up_a = is_t ? tu_slot : su_slot;
    const int* lo_a = is_t ? tl_slot : sl_slot;
    const int* ui_a = is_t ? tu : su;
    const int* li_a = is_t ? tl : sl;
    const float* Pq = is_t ? P_t : P_s;
    float* dstp     = is_t ? &tg_lds[0][0][0] : &sg_lds[0][0][0];

    // rolling uniform locs: lB[r]=loc[t+1], lC[r]=loc[t+2]
    int lB[RB], lC[RB], l0[RB];
    #pragma unroll
    for (int r = 0; r < RB; ++r) {
        const int tb = (b0 + r) * T_;
        l0[r] = __builtin_amdgcn_readfirstlane(traj[tb]);
        lB[r] = __builtin_amdgcn_readfirstlane(traj[tb + t1c]);
        lC[r] = __builtin_amdgcn_readfirstlane(traj[tb + t2c]);
    }

    // gate state
    float w[52];
    float gA[RB] = {0.f,0.f,0.f,0.f}, gB[RB] = {0.f,0.f,0.f,0.f};
    float c_reg[RB] = {0.f,0.f,0.f,0.f};
    if (isGate) {
        #pragma unroll
        for (int j = 0; j < 52; ++j) {
            const int k = kbase + j;
            w[j] = (k < 100) ? W_hh[k * 400 + n] : 0.f;
        }
        if (half == 0) {
            #pragma unroll
            for (int r = 0; r < RB; ++r) gA[r] = P[l0[r] * NC + n];
        }
    }

    // ts state: set A = inputs for tsg(1); set B filled during step 0
    int   uA[RB]={0,0,0,0}, lsA[RB]={0,0,0,0}, uiA[RB]={0,0,0,0}, liA[RB]={0,0,0,0};
    int   uB[RB]={0,0,0,0}, lsB[RB]={0,0,0,0}, uiB[RB]={0,0,0,0}, liB[RB]={0,0,0,0};
    float gpA[RB]={0.f,0.f,0.f,0.f}, gpB[RB]={0.f,0.f,0.f,0.f};
    if (isTS) {
        #pragma unroll
        for (int r = 0; r < RB; ++r) {
            const int tb = (b0 + r) * T_;
            // tsg(0) directly into buffer 0
            const float fu = (float)up_a[tb];
            const float fl = (float)lo_a[tb];
            const int   iu = ui_a[tb], il = li_a[tb];
            const float gp = P[l0[r] * NC + gcol];
            const float iv = (fu * Pq[il * H_ + hx] + fl * Pq[iu * H_ + hx])
                             / fmaxf(fu + fl, 1.f);
            dstp[r * H_ + hx] = 1.f / (1.f + expf(-(gp + iv)));
            // prefetch set A (inputs for tsg(1))
            const int off1 = tb + t1c;
            uA[r] = up_a[off1]; lsA[r] = lo_a[off1];
            uiA[r] = ui_a[off1]; liA[r] = li_a[off1];
            gpA[r] = P[lB[r] * NC + gcol];
        }
    }
    __syncthreads();

// One recurrence step. CBc = t&1 (compile-time). Gc/Gn = gate-gather cur/next
// register sets; U*/L* = ts input cur/next sets. Ends with raw barrier that
// drains LDS only; global prefetches stay in flight across it.
#define STEP(tt, CBc, Gc, Gn, Uc,Lc,UIc,LIc,GPc, Un,Ln,UIn,LIn,GPn)              \
  {                                                                              \
    constexpr int CB = (CBc); constexpr int NB = CB ^ 1;                         \
    const int tD = ((tt) + 3 < steps) ? (tt) + 3 : steps - 1;                    \
    const int t2 = ((tt) + 2 < steps) ? (tt) + 2 : steps - 1;                    \
    int nD[RB] = {0,0,0,0};                                                      \
    if (isGate || isTS) {                                                        \
      _Pragma("unroll")                                                          \
      for (int r = 0; r < RB; ++r)                                               \
        nD[r] = __builtin_amdgcn_readfirstlane(traj[(b0 + r) * T_ + tD]);        \
    }                                                                            \
    if (isGate) {                                                                \
      /* prefetch gate P-row gathers for tt+1 (half0 lanes only) */              \
      if (half == 0) {                                                           \
        _Pragma("unroll")                                                        \
        for (int r = 0; r < RB; ++r) Gn[r] = P[lB[r] * NC + n];                  \
      }                                                                          \
      /* h @ W_hh over this thread's k-slice */                                  \
      float acc[RB];                                                             \
      _Pragma("unroll")                                                          \
      for (int r = 0; r < RB; ++r) acc[r] = half ? 0.f : Gc[r];                  \
      _Pragma("unroll")                                                          \
      for (int k4 = 0; k4 < 13; ++k4) {                                          \
        _Pragma("unroll")                                                        \
        for (int r = 0; r < RB; ++r) {                                           \
          const float4 hv = *(const float4*)&h_lds[CB][r][kbase + k4 * 4];       \
          acc[r] += hv.x * w[k4 * 4 + 0];                                        \
          acc[r] += hv.y * w[k4 * 4 + 1];                                        \
          acc[r] += hv.z * w[k4 * 4 + 2];                                        \
          acc[r] += hv.w * w[k4 * 4 + 3];                                        \
        }                                                                        \
      }                                                                          \
      _Pragma("unroll")                                                          \
      for (int r = 0; r < RB; ++r) {                                             \
        const float v = acc[r] + __shfl_xor(acc[r], 1);   /* combine halves */   \
        const bool isg = (gi == 2);                                              \
        const float x  = isg ? 2.f * v : v;                                      \
        const float s  = 1.f / (1.f + expf(-x));                                 \
        const float a  = isg ? 2.f * s - 1.f : s;                                \
        const float b2 = __shfl_xor(a, 2);                                       \
        const float b4 = __shfl_xor(a, 4);                                       \
        const float b6 = __shfl_xor(b2, 4);                                      \
        if (gi == 0) {   /* a=i, b2=f, b4=g, b6=o */                             \
          const float tsv = tg_lds[CB][r][q] * sg_lds[CB][r][q];                 \
          c_reg[r] = b2 * c_reg[r] + a * tsv * b4;                               \
          if (half == 0) h_lds[NB][r][q] = b6 * tanhf(c_reg[r]);                 \
        }                                                                        \
      }                                                                          \
    }                                                                            \
    if (isTS) {                                                                  \
      _Pragma("unroll")                                                          \
      for (int r = 0; r < RB; ++r) {                                             \
        /* prefetch inputs for tsg(tt+2) (consumed next step) */                 \
        const int off2 = (b0 + r) * T_ + t2;                                     \
        Un[r]  = up_a[off2]; Ln[r]  = lo_a[off2];                                \
        UIn[r] = ui_a[off2]; LIn[r] = li_a[off2];                                \
        GPn[r] = P[lC[r] * NC + gcol];                                           \
        /* compute tsg(tt+1) from prefetched cur set */                          \
        const float pql = Pq[LIc[r] * H_ + hx];                                  \
        const float pqu = Pq[UIc[r] * H_ + hx];                                  \
        const float fu  = (float)Uc[r], fl = (float)Lc[r];                       \
        const float iv  = (fu * pql + fl * pqu) / fmaxf(fu + fl, 1.f);           \
        dstp[NB * (RB * H_) + r * H_ + hx] =                                     \
            1.f / (1.f + expf(-(GPc[r] + iv)));                                  \
      }                                                                          \
    }                                                                            \
    if (isGate || isTS) {                                                        \
      _Pragma("unroll")                                                          \
      for (int r = 0; r < RB; ++r) { lB[r] = lC[r]; lC[r] = nD[r]; }             \
    }                                                                            \
    asm volatile("s_waitcnt lgkmcnt(0)\n\ts_barrier" ::: "memory");              \
  }

    int t = 0;
    for (; t + 1 < steps; t += 2) {
        STEP(t,     0, gA, gB, uA,lsA,uiA,liA,gpA, uB,lsB,uiB,liB,gpB)
        STEP(t + 1, 1, gB, gA, uB,lsB,uiB,liB,gpB, uA,lsA,uiA,liA,gpA)
    }
    if (t < steps) {
        STEP(t, 0, gA, gB, uA,lsA,uiA,liA,gpA, uB,lsB,uiB,liB,gpB)
    }
#undef STEP

    if (tid < RB * H_) {
        const int r  = tid / H_;
        const int qq = tid - r * H_;
        out[(b0 + r) * H_ + qq] = h_lds[steps & 1][r][qq];
    }
}

// ---------------------------------------------------------------------------
extern "C" void kernel_launch(void* const* d_in, const int* in_sizes, int n_in,
                              void* d_out, int out_size, void* d_ws, size_t ws_size,
                              hipStream_t stream) {
    const int*   traj     = (const int*)  d_in[0];
    // d_in[1] = lennew (unused by the reference)
    const int*   traj_len = (const int*)  d_in[2];
    const int*   tu       = (const int*)  d_in[3];
    const int*   tl       = (const int*)  d_in[4];
    const int*   tu_slot  = (const int*)  d_in[5];
    const int*   tl_slot  = (const int*)  d_in[6];
    const int*   su       = (const int*)  d_in[7];
    const int*   sl       = (const int*)  d_in[8];
    const int*   su_slot  = (const int*)  d_in[9];
    const int*   sl_slot  = (const int*)  d_in[10];
    const float* emb_loc  = (const float*)d_in[11];
    const float* emb_t    = (const float*)d_in[12];
    const float* emb_s    = (const float*)d_in[13];
    const float* W_ih     = (const float*)d_in[14];
    const float* W_hh     = (const float*)d_in[15];
    const float* b        = (const float*)d_in[16];
    const float* W_xt     = (const float*)d_in[17];
    const float* W_tt     = (const float*)d_in[18];
    const float* b_t      = (const float*)d_in[19];
    const float* W_xs     = (const float*)d_in[20];
    const float* W_ss     = (const float*)d_in[21];
    const float* b_s      = (const float*)d_in[22];

    float* P   = (float*)d_ws;              // 40001*600 floats (96.0 MB)
    float* P_t = P + (size_t)LOCN * NC;     // 9200 floats
    float* P_s = P_t + 92 * H_;             // 9200 floats

    proj_loc_kernel<<<(LOCN + PROWS - 1) / PROWS, 320, 0, stream>>>(
        emb_loc, W_ih, W_xt, W_xs, b, b_t, b_s, P);
    proj_ts_kernel<<<(2 * 92 * H_ + 255) / 256, 256, 0, stream>>>(
        emb_t, emb_s, W_tt, W_ss, P_t, P_s);
    lstm_rec_kernel<<<B_ / RB, NT, 0, stream>>>(
        traj, traj_len, tu, tl, tu_slot, tl_slot, su, sl, su_slot, sl_slot,
        P, P_t, P_s, W_hh, (float*)d_out);
}

// Round 3
// 832.533 us; speedup vs baseline: 14.7037x; 14.7037x over previous
//
#include <hip/hip_runtime.h>

#define B_    1024
#define T_    256
#define LOCN  40001
#define E_    100
#define H_    100
#define NC    600   // [0,400): gates (i|f|g|o) preact, [400,500): t preact, [500,600): s preact

// ---------------------------------------------------------------------------
// Kernel 1: P_loc[LOC][600] = emb_loc @ [W_ih | W_xt | W_xs] + [b | b_t | b_s]
// (round-0 proven version, PROWS=16)
// ---------------------------------------------------------------------------
constexpr int PROWS = 16;
constexpr int PPAD  = 20;   // pad 16->20 dwords: keeps 16B alignment for b128, breaks pow2 bank stride

__global__ __launch_bounds__(320) void proj_loc_kernel(
    const float* __restrict__ emb_loc,
    const float* __restrict__ W_ih,   // [100][400]
    const float* __restrict__ W_xt,   // [100][100]
    const float* __restrict__ W_xs,   // [100][100]
    const float* __restrict__ b,      // [400]
    const float* __restrict__ b_t,    // [100]
    const float* __restrict__ b_s,    // [100]
    float* __restrict__ P)            // [LOC][600]
{
    __shared__ __attribute__((aligned(16))) float aT[E_][PPAD];  // transposed tile
    const int tid  = threadIdx.x;
    const int row0 = blockIdx.x * PROWS;

    for (int i = tid; i < PROWS * E_; i += 320) {
        int r = i / E_, k = i - r * E_;
        int rr = row0 + r;
        float v = 0.f;
        if (rr < LOCN) v = emb_loc[rr * E_ + k];
        aT[k][r] = v;
    }
    __syncthreads();
    if (tid >= 300) return;

    for (int cc = 0; cc < 2; ++cc) {
        const int c = tid + cc * 300;
        const float* wp; int stride; float bias;
        if (c < 400)      { wp = W_ih + c;         stride = 400; bias = b[c]; }
        else if (c < 500) { wp = W_xt + (c - 400); stride = 100; bias = b_t[c - 400]; }
        else              { wp = W_xs + (c - 500); stride = 100; bias = b_s[c - 500]; }

        float acc[PROWS];
        #pragma unroll
        for (int r = 0; r < PROWS; ++r) acc[r] = bias;

        for (int k = 0; k < E_; ++k) {
            float w = wp[(size_t)k * stride];
            #pragma unroll
            for (int r = 0; r < PROWS; ++r) acc[r] += aT[k][r] * w;
        }
        #pragma unroll
        for (int r = 0; r < PROWS; ++r) {
            int rr = row0 + r;
            if (rr < LOCN) P[(size_t)rr * NC + c] = acc[r];
        }
    }
}

// ---------------------------------------------------------------------------
// Kernel 2: P_t[92][100] = emb_t @ W_tt ; P_s[92][100] = emb_s @ W_ss
// ---------------------------------------------------------------------------
__global__ void proj_ts_kernel(
    const float* __restrict__ emb_t, const float* __restrict__ emb_s,
    const float* __restrict__ W_tt,  const float* __restrict__ W_ss,
    float* __restrict__ P_t, float* __restrict__ P_s)
{
    int idx = blockIdx.x * 256 + threadIdx.x;
    if (idx >= 2 * 92 * H_) return;
    int which = idx / (92 * H_);
    int rem   = idx - which * (92 * H_);
    int r = rem / H_, c = rem - r * H_;
    const float* e = which ? emb_s : emb_t;
    const float* W = which ? W_ss : W_tt;
    float acc = 0.f;
    #pragma unroll
    for (int k = 0; k < 12; ++k) acc += e[r * 12 + k] * W[k * H_ + c];
    (which ? P_s : P_t)[rem] = acc;
}

// ---------------------------------------------------------------------------
// Kernel 3: the recurrence. grid = 256 blocks, 4 batch rows/block, 704 thr.
// EXACT round-0 structure (685 us proven). ONE change: after loading the
// W_hh column into w[100], each element is pinned with an empty asm
// ("+v") so the value is asm-defined and regalloc CANNOT rematerialize the
// invariant global load inside the step loop. Round-0 counters (VGPR=84,
// WRITE=output-only, FETCH=gathers-only) prove the compiler was re-streaming
// W_hh from L2 every step (160 KB/block/step + ~100 addr-VALU/thread/step).
// Pinning forces w into registers: 400 thr x 100 VGPR = 160 KB of the CU's
// 512 KB file; launch-bounds cap for 704-thr blocks is ~170 VGPR -> fits.
// ---------------------------------------------------------------------------
constexpr int RB = 4;
constexpr int NT = 704;

__global__ __launch_bounds__(NT, 3) void lstm_rec_kernel(
    const int* __restrict__ traj,
    const int* __restrict__ traj_len_p,
    const int* __restrict__ tu,      const int* __restrict__ tl,
    const int* __restrict__ tu_slot, const int* __restrict__ tl_slot,
    const int* __restrict__ su,      const int* __restrict__ sl,
    const int* __restrict__ su_slot, const int* __restrict__ sl_slot,
    const float* __restrict__ P,     // [LOC][600]
    const float* __restrict__ P_t,   // [92][100]
    const float* __restrict__ P_s,   // [92][100]
    const float* __restrict__ W_hh,  // [100][400]
    float* __restrict__ out)         // [B][100]
{
    __shared__ __attribute__((aligned(16))) float h_lds[RB][H_];
    __shared__ float gates_lds[RB][400];
    __shared__ float tg_lds[RB][H_];
    __shared__ float sg_lds[RB][H_];
    __shared__ int   loc_lds[2][RB];

    const int tid = threadIdx.x;
    const int b0  = blockIdx.x * RB;
    int steps = traj_len_p[0] + 1;
    if (steps > T_) steps = T_;

    // W_hh column -> registers (persist across all 256 steps)
    float w[H_];
    if (tid < 400) {
        #pragma unroll
        for (int k = 0; k < H_; ++k) w[k] = W_hh[k * 400 + tid];
        // Pin: value becomes asm-defined -> not rematerializable -> must be
        // register-allocated (not re-loaded from L2 each step).
        #pragma unroll
        for (int k = 0; k < H_; ++k) asm volatile("" : "+v"(w[k]));
        ((float*)h_lds)[tid] = 0.f;
    }
    if (tid < RB) loc_lds[0][tid] = traj[(b0 + tid) * T_];

    const int er = tid / 100;        // epilogue row   (valid for tid<400)
    const int eh = tid - er * 100;   // epilogue h-idx
    float c_reg = 0.f, hval = 0.f;
    __syncthreads();

    for (int t = 0; t < steps; ++t) {
        const int buf = t & 1;

        if (tid >= 700) {                       // prefetch next step's locations
            int r = tid - 700;
            if (t + 1 < steps) loc_lds[buf ^ 1][r] = traj[(b0 + r) * T_ + t + 1];
        }

        if (tid < 400) {                        // ---- gates: gather + h @ W_hh ----
            const int n = tid;
            float gacc[RB];
            #pragma unroll
            for (int r = 0; r < RB; ++r)
                gacc[r] = P[(size_t)loc_lds[buf][r] * NC + n];

            float acc[RB] = {0.f, 0.f, 0.f, 0.f};
            #pragma unroll
            for (int k4 = 0; k4 < H_ / 4; ++k4) {
                #pragma unroll
                for (int r = 0; r < RB; ++r) {
                    float4 hv = *(const float4*)(&h_lds[r][k4 * 4]);
                    acc[r] += hv.x * w[k4 * 4 + 0];
                    acc[r] += hv.y * w[k4 * 4 + 1];
                    acc[r] += hv.z * w[k4 * 4 + 2];
                    acc[r] += hv.w * w[k4 * 4 + 3];
                }
            }
            const bool isg = (n >= 200 && n < 300);   // g-gate -> tanh via 2*sig(2x)-1
            #pragma unroll
            for (int r = 0; r < RB; ++r) {
                float v  = acc[r] + gacc[r];
                float xx = isg ? 2.f * v : v;
                float s  = 1.f / (1.f + expf(-xx));
                gates_lds[r][n] = isg ? (2.f * s - 1.f) : s;
            }
        }

        if (tid >= 448 && tid < 648) {          // ---- t/s gates (h-independent) ----
            const int  ch   = tid - 448;        // 0..199
            const bool is_t = ch < 100;
            const int  hx   = is_t ? ch : ch - 100;
            const int* up_a = is_t ? tu_slot : su_slot;
            const int* lo_a = is_t ? tl_slot : sl_slot;
            const int* ui_a = is_t ? tu : su;
            const int* li_a = is_t ? tl : sl;
            const float* Pq = is_t ? P_t : P_s;
            float* dst      = is_t ? &tg_lds[0][0] : &sg_lds[0][0];
            #pragma unroll
            for (int r = 0; r < RB; ++r) {
                const int off = (b0 + r) * T_ + t;
                float gp  = P[(size_t)loc_lds[buf][r] * NC + 400 + ch];
                float up  = (float)up_a[off];
                float low = (float)lo_a[off];
                int   ui  = ui_a[off], li = li_a[off];
                // interp(up_e,low_e,up,low) @ W = (up*Pq[low_idx] + low*Pq[up_idx]) / max(up+low,1)
                float iv  = (up * Pq[li * H_ + hx] + low * Pq[ui * H_ + hx])
                            / fmaxf(up + low, 1.f);
                float pre = gp + iv;
                dst[r * H_ + hx] = 1.f / (1.f + expf(-pre));
            }
        }
        __syncthreads();

        if (tid < 400) {                        // ---- epilogue: c,h update ----
            float i_g = gates_lds[er][eh];
            float f_g = gates_lds[er][100 + eh];
            float g_g = gates_lds[er][200 + eh];
            float o_g = gates_lds[er][300 + eh];
            float tsg = tg_lds[er][eh] * sg_lds[er][eh];
            c_reg = f_g * c_reg + i_g * tsg * g_g;
            hval  = o_g * tanhf(c_reg);
            h_lds[er][eh] = hval;
        }
        __syncthreads();
    }

    if (tid < 400) out[b0 * H_ + tid] = hval;
}

// ---------------------------------------------------------------------------
extern "C" void kernel_launch(void* const* d_in, const int* in_sizes, int n_in,
                              void* d_out, int out_size, void* d_ws, size_t ws_size,
                              hipStream_t stream) {
    const int*   traj     = (const int*)  d_in[0];
    // d_in[1] = lennew (unused by the reference)
    const int*   traj_len = (const int*)  d_in[2];
    const int*   tu       = (const int*)  d_in[3];
    const int*   tl       = (const int*)  d_in[4];
    const int*   tu_slot  = (const int*)  d_in[5];
    const int*   tl_slot  = (const int*)  d_in[6];
    const int*   su       = (const int*)  d_in[7];
    const int*   sl       = (const int*)  d_in[8];
    const int*   su_slot  = (const int*)  d_in[9];
    const int*   sl_slot  = (const int*)  d_in[10];
    const float* emb_loc  = (const float*)d_in[11];
    const float* emb_t    = (const float*)d_in[12];
    const float* emb_s    = (const float*)d_in[13];
    const float* W_ih     = (const float*)d_in[14];
    const float* W_hh     = (const float*)d_in[15];
    const float* b        = (const float*)d_in[16];
    const float* W_xt     = (const float*)d_in[17];
    const float* W_tt     = (const float*)d_in[18];
    const float* b_t      = (const float*)d_in[19];
    const float* W_xs     = (const float*)d_in[20];
    const float* W_ss     = (const float*)d_in[21];
    const float* b_s      = (const float*)d_in[22];

    float* P   = (float*)d_ws;              // 40001*600 = 24,000,600 floats (96.0 MB)
    float* P_t = P + (size_t)LOCN * NC;     // 9200 floats
    float* P_s = P_t + 92 * H_;             // 9200 floats

    proj_loc_kernel<<<(LOCN + PROWS - 1) / PROWS, 320, 0, stream>>>(
        emb_loc, W_ih, W_xt, W_xs, b, b_t, b_s, P);
    proj_ts_kernel<<<(2 * 92 * H_ + 255) / 256, 256, 0, stream>>>(
        emb_t, emb_s, W_tt, W_ss, P_t, P_s);
    lstm_rec_kernel<<<B_ / RB, NT, 0, stream>>>(
        traj, traj_len, tu, tl, tu_slot, tl_slot, su, sl, su_slot, sl_slot,
        P, P_t, P_s, W_hh, (float*)d_out);
}